// Round 1
// baseline (8671.857 us; speedup 1.0000x reference)
//
#include <hip/hip_runtime.h>
#include <math.h>

#define T_STEPS 128
#define B_SZ 256
#define AD 16
#define ZD 32
#define KM 8
#define HID 128
#define G4H 512
#define GPB 2
#define NTHR 512

// ws layout (float offsets)
#define WS_WIH0Q 0        // 8192  : [4][512][4]   W_ih0 transposed, float4-interleaved
#define WS_WHH0Q 8192     // 65536 : [32][512][4]
#define WS_WIH1Q 73728    // 65536
#define WS_WHH1Q 139264   // 65536
#define WS_BS0   204800   // 512   b_ih0+b_hh0
#define WS_BS1   205312   // 512
#define WS_Q     205824   // 1024  Q = QL QL^T + 1e-3 I
#define WS_R     206848   // 256   R = RL RL^T + 1e-3 I
#define WS_TOTAL 207104

__global__ void ssm_prep_kernel(const float* __restrict__ Wih0, const float* __restrict__ Whh0,
                                const float* __restrict__ Wih1, const float* __restrict__ Whh1,
                                const float* __restrict__ bih0, const float* __restrict__ bhh0,
                                const float* __restrict__ bih1, const float* __restrict__ bhh1,
                                const float* __restrict__ QL, const float* __restrict__ RL,
                                float* __restrict__ ws) {
  int tid = blockIdx.x * blockDim.x + threadIdx.x;
  int nt = gridDim.x * blockDim.x;
  for (int e = tid; e < G4H * AD; e += nt) {
    int j = e / AD, k = e % AD;
    ws[WS_WIH0Q + ((k >> 2) * G4H + j) * 4 + (k & 3)] = Wih0[e];
  }
  for (int e = tid; e < G4H * HID; e += nt) {
    int j = e >> 7, k = e & 127;
    int off = ((k >> 2) * G4H + j) * 4 + (k & 3);
    ws[WS_WHH0Q + off] = Whh0[e];
    ws[WS_WIH1Q + off] = Wih1[e];
    ws[WS_WHH1Q + off] = Whh1[e];
  }
  for (int e = tid; e < G4H; e += nt) {
    ws[WS_BS0 + e] = bih0[e] + bhh0[e];
    ws[WS_BS1 + e] = bih1[e] + bhh1[e];
  }
  for (int e = tid; e < ZD * ZD; e += nt) {
    int i = e >> 5, j = e & 31;
    float s = 0.f;
    for (int k = 0; k < ZD; ++k) s += QL[i * ZD + k] * QL[j * ZD + k];
    if (i == j) s += 0.001f;
    ws[WS_Q + e] = s;
  }
  for (int e = tid; e < AD * AD; e += nt) {
    int i = e >> 4, j = e & 15;
    float s = 0.f;
    for (int k = 0; k < AD; ++k) s += RL[i * AD + k] * RL[j * AD + k];
    if (i == j) s += 0.001f;
    ws[WS_R + e] = s;
  }
}

struct alignas(16) BS {
  float h0[HID], c0[HID], h1[HID], c1[HID];
  float g[G4H];
  float a[AD];
  float w[KM];
  float meanp[ZD], meant[ZD], r[AD];
  float P[ZD * ZD];       // cov_p
  float An[ZD * ZD];      // A_next
  float C[AD * ZD];       // C from current weight
  float CP[AD * ZD];      // C @ cov_p
  float Aug[2][AD * 2 * AD]; // Gauss-Jordan ping-pong [S | I] -> [I | invS]
  float Kk[ZD * AD];      // Kalman gain 32x16
  float Ct[ZD * ZD];      // cov_t (unsym), reused for M
  float ACt[ZD * ZD];     // A_next @ sym(cov_t)
};

__device__ __forceinline__ float sigm(float x) { return 1.0f / (1.0f + expf(-x)); }
__device__ __forceinline__ float d4(const float4& w, const float4& x) {
  return w.x * x.x + w.y * x.y + w.z * x.z + w.w * x.w;
}

__global__ void __launch_bounds__(NTHR) ssm_main_kernel(
    const float* __restrict__ as_, const float* __restrict__ AK, const float* __restrict__ CK,
    const float* __restrict__ initm, const float* __restrict__ initc,
    const float* __restrict__ Wout, const float* __restrict__ bout,
    const float* __restrict__ ws, float* __restrict__ out) {
  __shared__ BS sb[GPB];
  const int tid = threadIdx.x;
  const int lb = tid >> 8;
  const int lt = tid & 255;
  const int b = blockIdx.x * GPB + lb;
  BS& s = sb[lb];

  float* o_means = out;
  float* o_covs = o_means + (size_t)T_STEPS * B_SZ * ZD;
  float* o_nmean = o_covs + (size_t)T_STEPS * B_SZ * ZD * ZD;
  float* o_ncovs = o_nmean + (size_t)T_STEPS * B_SZ * ZD;
  float* o_As = o_ncovs + (size_t)T_STEPS * B_SZ * ZD * ZD;
  float* o_Cs = o_As + (size_t)(T_STEPS + 1) * B_SZ * ZD * ZD;
  float* o_a = o_Cs + (size_t)(T_STEPS + 1) * B_SZ * AD * ZD;

  const float* bs0 = ws + WS_BS0;
  const float* bs1 = ws + WS_BS1;
  const float* Qm = ws + WS_Q;
  const float* Rm = ws + WS_R;
  const float4* Wi0q = (const float4*)(ws + WS_WIH0Q);
  const float4* Wh0q = (const float4*)(ws + WS_WHH0Q);
  const float4* Wi1q = (const float4*)(ws + WS_WIH1Q);
  const float4* Wh1q = (const float4*)(ws + WS_WHH1Q);

  // ---- init carry ----
  for (int e = lt; e < HID; e += 256) { s.h0[e] = 0.f; s.c0[e] = 0.f; s.h1[e] = 0.f; s.c1[e] = 0.f; }
  for (int e = lt; e < ZD * ZD; e += 256) s.P[e] = initc[e];
  if (lt < ZD) s.meanp[lt] = initm[lt];
  if (lt < KM) s.w[lt] = 1.0f;
  __syncthreads();

  for (int t = 0; t < T_STEPS; ++t) {
    const size_t tb = (size_t)(t * B_SZ + b);

    // ---- P0: load a_t (+a_out), C_cur -> LDS+out, A_cur -> out (uses carry weight) ----
    if (lt < AD) {
      float v = as_[tb * AD + lt];
      s.a[lt] = v;
      o_a[tb * AD + lt] = v;
    }
    for (int e = lt; e < AD * ZD; e += 256) {
      float acc = 0.f;
      #pragma unroll
      for (int k = 0; k < KM; ++k) acc += s.w[k] * CK[k * AD * ZD + e];
      s.C[e] = acc;
      o_Cs[tb * (AD * ZD) + e] = acc;
    }
    for (int e = lt; e < ZD * ZD; e += 256) {
      float acc = 0.f;
      #pragma unroll
      for (int k = 0; k < KM; ++k) acc += s.w[k] * AK[k * ZD * ZD + e];
      o_As[tb * (ZD * ZD) + e] = acc;
    }
    __syncthreads();

    // ---- P1: LSTM layer-0 gates (thread j = gate j, both batches) + CP + residual r ----
    {
      const int j = tid;
      float acc0 = bs0[j];
      float acc1 = acc0;
      #pragma unroll
      for (int k4 = 0; k4 < 4; ++k4) {
        float4 wv = Wi0q[k4 * G4H + j];
        float4 xa = *(const float4*)&sb[0].a[k4 * 4];
        float4 xb = *(const float4*)&sb[1].a[k4 * 4];
        acc0 += d4(wv, xa);
        acc1 += d4(wv, xb);
      }
      #pragma unroll 8
      for (int k4 = 0; k4 < 32; ++k4) {
        float4 wv = Wh0q[k4 * G4H + j];
        float4 xa = *(const float4*)&sb[0].h0[k4 * 4];
        float4 xb = *(const float4*)&sb[1].h0[k4 * 4];
        acc0 += d4(wv, xa);
        acc1 += d4(wv, xb);
      }
      sb[0].g[j] = acc0;
      sb[1].g[j] = acc1;
    }
    for (int e = lt; e < AD * ZD; e += 256) {
      int i = e >> 5, jj = e & 31;
      float acc = 0.f;
      #pragma unroll
      for (int k = 0; k < ZD; ++k) acc += s.C[i * ZD + k] * s.P[k * ZD + jj];
      s.CP[e] = acc;
    }
    if (lt < AD) {
      float acc = s.a[lt];
      #pragma unroll
      for (int k = 0; k < ZD; ++k) acc -= s.C[lt * ZD + k] * s.meanp[k];
      s.r[lt] = acc;
    }
    __syncthreads();

    // ---- P2: layer-0 h/c update + S = CP C^T + R -> Aug[0] = [S | I] ----
    if (lt < HID) {
      float ig = sigm(s.g[lt]);
      float fg = sigm(s.g[HID + lt]);
      float gg = tanhf(s.g[2 * HID + lt]);
      float og = sigm(s.g[3 * HID + lt]);
      float c2 = fg * s.c0[lt] + ig * gg;
      s.c0[lt] = c2;
      s.h0[lt] = og * tanhf(c2);
    }
    {
      int i = lt >> 4, jj = lt & 15;
      float acc = Rm[lt];
      #pragma unroll
      for (int k = 0; k < ZD; ++k) acc += s.CP[i * ZD + k] * s.C[jj * ZD + k];
      s.Aug[0][i * 2 * AD + jj] = acc;
      s.Aug[0][i * 2 * AD + AD + jj] = (i == jj) ? 1.0f : 0.0f;
    }
    __syncthreads();

    // ---- P3: LSTM layer-1 gates ----
    {
      const int j = tid;
      float acc0 = bs1[j];
      float acc1 = acc0;
      #pragma unroll 8
      for (int k4 = 0; k4 < 32; ++k4) {
        float4 wv = Wi1q[k4 * G4H + j];
        float4 xa = *(const float4*)&sb[0].h0[k4 * 4];
        float4 xb = *(const float4*)&sb[1].h0[k4 * 4];
        acc0 += d4(wv, xa);
        acc1 += d4(wv, xb);
      }
      #pragma unroll 8
      for (int k4 = 0; k4 < 32; ++k4) {
        float4 wv = Wh1q[k4 * G4H + j];
        float4 xa = *(const float4*)&sb[0].h1[k4 * 4];
        float4 xb = *(const float4*)&sb[1].h1[k4 * 4];
        acc0 += d4(wv, xa);
        acc1 += d4(wv, xb);
      }
      sb[0].g[j] = acc0;
      sb[1].g[j] = acc1;
    }
    __syncthreads();

    // ---- P4: layer-1 h/c update ----
    if (lt < HID) {
      float ig = sigm(s.g[lt]);
      float fg = sigm(s.g[HID + lt]);
      float gg = tanhf(s.g[2 * HID + lt]);
      float og = sigm(s.g[3 * HID + lt]);
      float c2 = fg * s.c1[lt] + ig * gg;
      s.c1[lt] = c2;
      s.h1[lt] = og * tanhf(c2);
    }
    __syncthreads();

    // ---- P5: logits (16 groups x 32 lanes) ----
    {
      int grp = tid >> 5;
      int l = tid & 31;
      int lb2 = grp >> 3, lg = grp & 7;
      float p = 0.f;
      #pragma unroll
      for (int i = l; i < HID; i += 32) p += Wout[lg * HID + i] * sb[lb2].h1[i];
      #pragma unroll
      for (int m = 16; m >= 1; m >>= 1) p += __shfl_xor(p, m, 32);
      if (l == 0) sb[lb2].g[lg] = p + bout[lg];
    }
    __syncthreads();

    // ---- P6: softmax -> new weight (overwrites s.w; old w is dead after P0) ----
    if (tid < GPB) {
      BS& sx = sb[tid];
      float mx = sx.g[0];
      #pragma unroll
      for (int k = 1; k < KM; ++k) mx = fmaxf(mx, sx.g[k]);
      float sum = 0.f;
      float ex[KM];
      #pragma unroll
      for (int k = 0; k < KM; ++k) { ex[k] = expf(sx.g[k] - mx); sum += ex[k]; }
      float inv = 1.0f / sum;
      #pragma unroll
      for (int k = 0; k < KM; ++k) sx.w[k] = ex[k] * inv;
    }
    __syncthreads();

    // ---- P7: A_next = einsum(w_next, A_K) ----
    for (int e = lt; e < ZD * ZD; e += 256) {
      float acc = 0.f;
      #pragma unroll
      for (int k = 0; k < KM; ++k) acc += s.w[k] * AK[k * ZD * ZD + e];
      s.An[e] = acc;
    }
    __syncthreads();

    // ---- Gauss-Jordan inversion of S (SPD, no pivoting), ping-pong, 1 barrier/iter ----
    for (int j = 0; j < AD; ++j) {
      const float* src = s.Aug[j & 1];
      float* dst = s.Aug[(j + 1) & 1];
      float pinv = 1.0f / src[j * 2 * AD + j];
      #pragma unroll
      for (int q = 0; q < 2; ++q) {
        int e = lt + q * 256;
        int i = e >> 5, k = e & 31;
        float v = src[e];
        float pj = src[j * 2 * AD + k];
        float f = src[i * 2 * AD + j];
        dst[e] = (i == j) ? v * pinv : v - f * pinv * pj;
      }
      __syncthreads();
    }
    const float* invS = s.Aug[0]; // right half: invS[i][jj] at [i*32 + 16 + jj]

    // ---- P8: K = CP^T @ invS (32x16) ----
    #pragma unroll
    for (int q = 0; q < 2; ++q) {
      int e = lt + q * 256;
      int i = e >> 4, jj = e & 15;
      float acc = 0.f;
      #pragma unroll
      for (int k = 0; k < AD; ++k) acc += s.CP[k * ZD + i] * invS[k * 2 * AD + AD + jj];
      s.Kk[i * AD + jj] = acc;
    }
    __syncthreads();

    // ---- P9: mean_t (+out), cov_t unsym -> Ct ----
    if (lt < ZD) {
      float acc = s.meanp[lt];
      #pragma unroll
      for (int k = 0; k < AD; ++k) acc += s.Kk[lt * AD + k] * s.r[k];
      s.meant[lt] = acc;
      o_means[tb * ZD + lt] = acc;
    }
    #pragma unroll
    for (int q = 0; q < 4; ++q) {
      int e = lt + q * 256;
      int i = e >> 5, jj = e & 31;
      float acc = 0.f;
      #pragma unroll
      for (int k = 0; k < AD; ++k) acc += s.Kk[i * AD + k] * s.CP[k * ZD + jj];
      s.Ct[e] = s.P[e] - acc;
    }
    __syncthreads();

    // ---- P10: covs out = sym(Ct), ACt = An @ sym(Ct), meanp' = An @ mean_t (+out) ----
    if (lt < ZD) {
      float acc = 0.f;
      #pragma unroll
      for (int k = 0; k < ZD; ++k) acc += s.An[lt * ZD + k] * s.meant[k];
      s.meanp[lt] = acc;
      o_nmean[tb * ZD + lt] = acc;
    }
    #pragma unroll
    for (int q = 0; q < 4; ++q) {
      int e = lt + q * 256;
      int i = e >> 5, jj = e & 31;
      o_covs[tb * (ZD * ZD) + e] = 0.5f * (s.Ct[e] + s.Ct[jj * ZD + i]);
      float acc = 0.f;
      #pragma unroll
      for (int k = 0; k < ZD; ++k) acc += s.An[i * ZD + k] * (0.5f * (s.Ct[k * ZD + jj] + s.Ct[jj * ZD + k]));
      s.ACt[e] = acc;
    }
    __syncthreads();

    // ---- P11: M = ACt @ An^T + Q -> Ct ----
    #pragma unroll
    for (int q = 0; q < 4; ++q) {
      int e = lt + q * 256;
      int i = e >> 5, jj = e & 31;
      float acc = Qm[e];
      #pragma unroll
      for (int k = 0; k < ZD; ++k) acc += s.ACt[i * ZD + k] * s.An[jj * ZD + k];
      s.Ct[e] = acc;
    }
    __syncthreads();

    // ---- P12: cov_p' = sym(M) (+ncovs out) ----
    #pragma unroll
    for (int q = 0; q < 4; ++q) {
      int e = lt + q * 256;
      int i = e >> 5, jj = e & 31;
      float v = 0.5f * (s.Ct[e] + s.Ct[jj * ZD + i]);
      s.P[e] = v;
      o_ncovs[tb * (ZD * ZD) + e] = v;
    }
    __syncthreads();
  }

  // ---- final A/C from final weight (index T) ----
  {
    const size_t tb = (size_t)(T_STEPS * B_SZ + b);
    for (int e = lt; e < ZD * ZD; e += 256) {
      float acc = 0.f;
      #pragma unroll
      for (int k = 0; k < KM; ++k) acc += s.w[k] * AK[k * ZD * ZD + e];
      o_As[tb * (ZD * ZD) + e] = acc;
    }
    for (int e = lt; e < AD * ZD; e += 256) {
      float acc = 0.f;
      #pragma unroll
      for (int k = 0; k < KM; ++k) acc += s.w[k] * CK[k * AD * ZD + e];
      o_Cs[tb * (AD * ZD) + e] = acc;
    }
  }
}

extern "C" void kernel_launch(void* const* d_in, const int* in_sizes, int n_in,
                              void* d_out, int out_size, void* d_ws, size_t ws_size,
                              hipStream_t stream) {
  const float* as_ = (const float*)d_in[0];
  const float* AK = (const float*)d_in[1];
  const float* CK = (const float*)d_in[2];
  const float* QL = (const float*)d_in[3];
  const float* RL = (const float*)d_in[4];
  const float* initm = (const float*)d_in[5];
  const float* initc = (const float*)d_in[6];
  const float* Wih0 = (const float*)d_in[7];
  const float* Whh0 = (const float*)d_in[8];
  const float* bih0 = (const float*)d_in[9];
  const float* bhh0 = (const float*)d_in[10];
  const float* Wih1 = (const float*)d_in[11];
  const float* Whh1 = (const float*)d_in[12];
  const float* bih1 = (const float*)d_in[13];
  const float* bhh1 = (const float*)d_in[14];
  const float* Wout = (const float*)d_in[15];
  const float* bout = (const float*)d_in[16];
  float* ws = (float*)d_ws;
  float* out = (float*)d_out;

  ssm_prep_kernel<<<256, 256, 0, stream>>>(Wih0, Whh0, Wih1, Whh1, bih0, bhh0, bih1, bhh1,
                                           QL, RL, ws);
  ssm_main_kernel<<<B_SZ / GPB, NTHR, 0, stream>>>(as_, AK, CK, initm, initc, Wout, bout, ws, out);
}

// Round 3
// 2985.107 us; speedup vs baseline: 2.9050x; 2.9050x over previous
//
#include <hip/hip_runtime.h>
#include <math.h>

#define T_STEPS 128
#define B_SZ 256
#define AD 16
#define ZD 32
#define KM 8
#define HID 128
#define G4H 512
#define NTHR 512
#define LDA 33   // padded stride for 32-col matrices
#define LDK 17   // padded stride for 16-col K

// ws layout (float offsets)
#define WS_WIH0Q 0        // 8192  : [4][512][4]   W_ih0 transposed, float4-interleaved
#define WS_WHH0Q 8192     // 65536 : [32][512][4]
#define WS_WIH1Q 73728    // 65536
#define WS_WHH1Q 139264   // 65536
#define WS_BS0   204800   // 512   b_ih0+b_hh0
#define WS_BS1   205312   // 512
#define WS_Q     205824   // 1024  Q = QL QL^T + 1e-3 I
#define WS_R     206848   // 256   R = RL RL^T + 1e-3 I

__global__ void ssm_prep_kernel(const float* __restrict__ Wih0, const float* __restrict__ Whh0,
                                const float* __restrict__ Wih1, const float* __restrict__ Whh1,
                                const float* __restrict__ bih0, const float* __restrict__ bhh0,
                                const float* __restrict__ bih1, const float* __restrict__ bhh1,
                                const float* __restrict__ QL, const float* __restrict__ RL,
                                float* __restrict__ ws) {
  int tid = blockIdx.x * blockDim.x + threadIdx.x;
  int nt = gridDim.x * blockDim.x;
  for (int e = tid; e < G4H * AD; e += nt) {
    int j = e / AD, k = e % AD;
    ws[WS_WIH0Q + ((k >> 2) * G4H + j) * 4 + (k & 3)] = Wih0[e];
  }
  for (int e = tid; e < G4H * HID; e += nt) {
    int j = e >> 7, k = e & 127;
    int off = ((k >> 2) * G4H + j) * 4 + (k & 3);
    ws[WS_WHH0Q + off] = Whh0[e];
    ws[WS_WIH1Q + off] = Wih1[e];
    ws[WS_WHH1Q + off] = Whh1[e];
  }
  for (int e = tid; e < G4H; e += nt) {
    ws[WS_BS0 + e] = bih0[e] + bhh0[e];
    ws[WS_BS1 + e] = bih1[e] + bhh1[e];
  }
  for (int e = tid; e < ZD * ZD; e += nt) {
    int i = e >> 5, j = e & 31;
    float s = 0.f;
    for (int k = 0; k < ZD; ++k) s += QL[i * ZD + k] * QL[j * ZD + k];
    if (i == j) s += 0.001f;
    ws[WS_Q + e] = s;
  }
  for (int e = tid; e < AD * AD; e += nt) {
    int i = e >> 4, j = e & 15;
    float s = 0.f;
    for (int k = 0; k < AD; ++k) s += RL[i * AD + k] * RL[j * AD + k];
    if (i == j) s += 0.001f;
    ws[WS_R + e] = s;
  }
}

struct alignas(16) BS {
  float h0[HID], c0[HID], h1[HID], c1[HID];
  float g[G4H];                // gates; low 8 reused for logits
  float a[AD];
  float w[KM];
  float meanp[ZD], meant[ZD], r[AD];
  float P[ZD * LDA];           // cov_p (padded)
  float An[ZD * LDA];          // A_next
  float C[AD * LDA];           // C from current weight
  float CP[AD * LDA];          // C @ cov_p
  float Aug[2][AD * LDA];      // Gauss-Jordan ping-pong [S | I]
  float Kk[ZD * LDK];          // Kalman gain 32x16
  float Ct[ZD * LDA];          // cov_t (unsym); reused for M
  float ACt[ZD * LDA];         // A_next @ sym(cov_t)
};

__device__ __forceinline__ float sigm(float x) { return 1.0f / (1.0f + expf(-x)); }
__device__ __forceinline__ float d4(const float4& w, const float4& x) {
  return w.x * x.x + w.y * x.y + w.z * x.z + w.w * x.w;
}

__global__ void __launch_bounds__(NTHR) ssm_main_kernel(
    const float* __restrict__ as_, const float* __restrict__ AK, const float* __restrict__ CK,
    const float* __restrict__ initm, const float* __restrict__ initc,
    const float* __restrict__ Wout, const float* __restrict__ bout,
    const float* __restrict__ ws, float* __restrict__ out) {
  __shared__ BS s;
  const int tid = threadIdx.x;
  const int b = blockIdx.x;

  float* o_means = out;
  float* o_covs = o_means + (size_t)T_STEPS * B_SZ * ZD;
  float* o_nmean = o_covs + (size_t)T_STEPS * B_SZ * ZD * ZD;
  float* o_ncovs = o_nmean + (size_t)T_STEPS * B_SZ * ZD;
  float* o_As = o_ncovs + (size_t)T_STEPS * B_SZ * ZD * ZD;
  float* o_Cs = o_As + (size_t)(T_STEPS + 1) * B_SZ * ZD * ZD;
  float* o_a = o_Cs + (size_t)(T_STEPS + 1) * B_SZ * AD * ZD;

  const float* bs0 = ws + WS_BS0;
  const float* bs1 = ws + WS_BS1;
  const float* Qm = ws + WS_Q;
  const float* Rm = ws + WS_R;
  const float4* Wi0q = (const float4*)(ws + WS_WIH0Q);
  const float4* Wh0q = (const float4*)(ws + WS_WHH0Q);
  const float4* Wi1q = (const float4*)(ws + WS_WIH1Q);
  const float4* Wh1q = (const float4*)(ws + WS_WHH1Q);

  // Gauss-Jordan elementwise step: 512 threads, 1 element each (16x32 augmented)
  auto gj_step = [&](int j) {
    const float* src = s.Aug[j & 1];
    float* dst = s.Aug[(j + 1) & 1];
    int i = tid >> 5, k = tid & 31;
    float pinv = 1.0f / src[j * LDA + j];
    float v = src[i * LDA + k];
    float pj = src[j * LDA + k];
    float f = src[i * LDA + j];
    dst[i * LDA + k] = (i == j) ? v * pinv : fmaf(-(f * pinv), pj, v);
  };

  // ---- init carry ----
  if (tid < HID) { s.h0[tid] = 0.f; s.c0[tid] = 0.f; s.h1[tid] = 0.f; s.c1[tid] = 0.f; }
  #pragma unroll
  for (int q = 0; q < 2; ++q) {
    int e = tid + q * NTHR;
    s.P[(e >> 5) * LDA + (e & 31)] = initc[e];
  }
  if (tid < ZD) s.meanp[tid] = initm[tid];
  if (tid < KM) s.w[tid] = 1.0f;
  __syncthreads();

  for (int t = 0; t < T_STEPS; ++t) {
    const size_t tb = (size_t)(t * B_SZ + b);

    // ---- P0: a_t load (+out), C_cur (LDS+out), A_cur (out) from carry weight ----
    if (tid < AD) {
      float v = as_[tb * AD + tid];
      s.a[tid] = v;
      o_a[tb * AD + tid] = v;
    }
    {
      int i = tid >> 5, jj = tid & 31;
      float acc = 0.f;
      #pragma unroll
      for (int k = 0; k < KM; ++k) acc += s.w[k] * CK[k * (AD * ZD) + tid];
      s.C[i * LDA + jj] = acc;
      o_Cs[tb * (AD * ZD) + tid] = acc;
    }
    #pragma unroll
    for (int q = 0; q < 2; ++q) {
      int e = tid + q * NTHR;
      float acc = 0.f;
      #pragma unroll
      for (int k = 0; k < KM; ++k) acc += s.w[k] * AK[k * (ZD * ZD) + e];
      o_As[tb * (ZD * ZD) + e] = acc;
    }
    __syncthreads();

    // ---- P1: L0 gates (1 gate/thread) + CP = C @ P + residual r ----
    {
      const int j = tid;
      float acc = bs0[j];
      #pragma unroll
      for (int k4 = 0; k4 < 4; ++k4)
        acc += d4(Wi0q[k4 * G4H + j], *(const float4*)&s.a[k4 * 4]);
      #pragma unroll 8
      for (int k4 = 0; k4 < 32; ++k4)
        acc += d4(Wh0q[k4 * G4H + j], *(const float4*)&s.h0[k4 * 4]);
      s.g[j] = acc;
    }
    {
      int i = tid >> 5, jj = tid & 31;  // 512 elems = 16x32
      float acc = 0.f;
      #pragma unroll
      for (int k = 0; k < ZD; ++k) acc += s.C[i * LDA + k] * s.P[k * LDA + jj];
      s.CP[i * LDA + jj] = acc;
    }
    if (tid < AD) {
      float acc = s.a[tid];
      #pragma unroll
      for (int k = 0; k < ZD; ++k) acc -= s.C[tid * LDA + k] * s.meanp[k];
      s.r[tid] = acc;
    }
    __syncthreads();

    // ---- P2: L0 h/c update + S = CP C^T + R -> Aug[0] = [S | I] ----
    if (tid < HID) {
      float ig = sigm(s.g[tid]);
      float fg = sigm(s.g[HID + tid]);
      float gg = tanhf(s.g[2 * HID + tid]);
      float og = sigm(s.g[3 * HID + tid]);
      float c2 = fg * s.c0[tid] + ig * gg;
      s.c0[tid] = c2;
      s.h0[tid] = og * tanhf(c2);
    }
    if (tid < AD * AD) {
      int i = tid >> 4, jj = tid & 15;
      float acc = Rm[tid];
      #pragma unroll
      for (int k = 0; k < ZD; ++k) acc += s.CP[i * LDA + k] * s.C[jj * LDA + k];
      s.Aug[0][i * LDA + jj] = acc;
      s.Aug[0][i * LDA + AD + jj] = (i == jj) ? 1.0f : 0.0f;
    }
    __syncthreads();

    // ---- GJ0 + L1 gates ----
    {
      const int j = tid;
      float acc = bs1[j];
      #pragma unroll 8
      for (int k4 = 0; k4 < 32; ++k4)
        acc += d4(Wi1q[k4 * G4H + j], *(const float4*)&s.h0[k4 * 4]);
      #pragma unroll 8
      for (int k4 = 0; k4 < 32; ++k4)
        acc += d4(Wh1q[k4 * G4H + j], *(const float4*)&s.h1[k4 * 4]);
      gj_step(0);
      s.g[j] = acc;
    }
    __syncthreads();

    // ---- GJ1 + L1 h/c update ----
    gj_step(1);
    if (tid < HID) {
      float ig = sigm(s.g[tid]);
      float fg = sigm(s.g[HID + tid]);
      float gg = tanhf(s.g[2 * HID + tid]);
      float og = sigm(s.g[3 * HID + tid]);
      float c2 = fg * s.c1[tid] + ig * gg;
      s.c1[tid] = c2;
      s.h1[tid] = og * tanhf(c2);
    }
    __syncthreads();

    // ---- GJ2 + logits (8 groups of 32 lanes) ----
    gj_step(2);
    {
      int grp = tid >> 5;
      int l = tid & 31;
      if (grp < KM) {
        float p = 0.f;
        #pragma unroll
        for (int i = l; i < HID; i += 32) p += Wout[grp * HID + i] * s.h1[i];
        #pragma unroll
        for (int m = 16; m >= 1; m >>= 1) p += __shfl_xor(p, m, 32);
        if (l == 0) s.g[grp] = p + bout[grp];
      }
    }
    __syncthreads();

    // ---- GJ3 + softmax (per-thread, redundant) + A_next einsum + w store ----
    gj_step(3);
    {
      float lg[KM];
      float mx = s.g[0];
      #pragma unroll
      for (int k = 1; k < KM; ++k) mx = fmaxf(mx, s.g[k]);
      float sum = 0.f;
      #pragma unroll
      for (int k = 0; k < KM; ++k) { lg[k] = expf(s.g[k] - mx); sum += lg[k]; }
      float inv = 1.0f / sum;
      #pragma unroll
      for (int k = 0; k < KM; ++k) lg[k] *= inv;
      if (tid < KM) s.w[tid] = lg[tid];
      #pragma unroll
      for (int q = 0; q < 2; ++q) {
        int e = tid + q * NTHR;
        float acc = 0.f;
        #pragma unroll
        for (int k = 0; k < KM; ++k) acc += lg[k] * AK[k * (ZD * ZD) + e];
        s.An[(e >> 5) * LDA + (e & 31)] = acc;
      }
    }
    __syncthreads();

    // ---- GJ4..GJ15 ----
    for (int j = 4; j < AD; ++j) {
      gj_step(j);
      __syncthreads();
    }
    const float* invS = s.Aug[0];  // right half: invS[i][jj] at [i*LDA + AD + jj]

    // ---- P8: K = CP^T @ invS (32x16) ----
    {
      int i = tid >> 4, jj = tid & 15;
      float acc = 0.f;
      #pragma unroll
      for (int k = 0; k < AD; ++k) acc += s.CP[k * LDA + i] * invS[k * LDA + AD + jj];
      s.Kk[i * LDK + jj] = acc;
    }
    __syncthreads();

    // ---- P9: mean_t (+out) + cov_t = P - K CP (unsym) ----
    if (tid < ZD) {
      float acc = s.meanp[tid];
      #pragma unroll
      for (int k = 0; k < AD; ++k) acc += s.Kk[tid * LDK + k] * s.r[k];
      s.meant[tid] = acc;
      o_means[tb * ZD + tid] = acc;
    }
    #pragma unroll
    for (int q = 0; q < 2; ++q) {
      int e = tid + q * NTHR;
      int i = e >> 5, jj = e & 31;
      float acc = 0.f;
      #pragma unroll
      for (int k = 0; k < AD; ++k) acc += s.Kk[i * LDK + k] * s.CP[k * LDA + jj];
      s.Ct[i * LDA + jj] = s.P[i * LDA + jj] - acc;
    }
    __syncthreads();

    // ---- P10: covs out = sym(Ct), ACt = An @ sym(Ct), meanp' = An @ mean_t (+out) ----
    if (tid < ZD) {
      float acc = 0.f;
      #pragma unroll
      for (int k = 0; k < ZD; ++k) acc += s.An[tid * LDA + k] * s.meant[k];
      s.meanp[tid] = acc;
      o_nmean[tb * ZD + tid] = acc;
    }
    #pragma unroll
    for (int q = 0; q < 2; ++q) {
      int e = tid + q * NTHR;
      int i = e >> 5, jj = e & 31;
      o_covs[tb * (ZD * ZD) + e] = 0.5f * (s.Ct[i * LDA + jj] + s.Ct[jj * LDA + i]);
      float acc = 0.f;
      #pragma unroll
      for (int k = 0; k < ZD; ++k)
        acc += s.An[i * LDA + k] * (0.5f * (s.Ct[k * LDA + jj] + s.Ct[jj * LDA + k]));
      s.ACt[i * LDA + jj] = acc;
    }
    __syncthreads();

    // ---- P11: M = ACt @ An^T + Q -> Ct ----
    #pragma unroll
    for (int q = 0; q < 2; ++q) {
      int e = tid + q * NTHR;
      int i = e >> 5, jj = e & 31;
      float acc = Qm[e];
      #pragma unroll
      for (int k = 0; k < ZD; ++k) acc += s.ACt[i * LDA + k] * s.An[jj * LDA + k];
      s.Ct[i * LDA + jj] = acc;
    }
    __syncthreads();

    // ---- P12: cov_p' = sym(M) -> P (+ncovs out) ----
    #pragma unroll
    for (int q = 0; q < 2; ++q) {
      int e = tid + q * NTHR;
      int i = e >> 5, jj = e & 31;
      float v = 0.5f * (s.Ct[i * LDA + jj] + s.Ct[jj * LDA + i]);
      s.P[i * LDA + jj] = v;
      o_ncovs[tb * (ZD * ZD) + e] = v;
    }
    __syncthreads();
  }

  // ---- final A/C from final weight (index T) ----
  {
    const size_t tb = (size_t)(T_STEPS * B_SZ + b);
    #pragma unroll
    for (int q = 0; q < 2; ++q) {
      int e = tid + q * NTHR;
      float acc = 0.f;
      #pragma unroll
      for (int k = 0; k < KM; ++k) acc += s.w[k] * AK[k * (ZD * ZD) + e];
      o_As[tb * (ZD * ZD) + e] = acc;
    }
    {
      float acc = 0.f;
      #pragma unroll
      for (int k = 0; k < KM; ++k) acc += s.w[k] * CK[k * (AD * ZD) + tid];
      o_Cs[tb * (AD * ZD) + tid] = acc;
    }
  }
}

extern "C" void kernel_launch(void* const* d_in, const int* in_sizes, int n_in,
                              void* d_out, int out_size, void* d_ws, size_t ws_size,
                              hipStream_t stream) {
  const float* as_ = (const float*)d_in[0];
  const float* AK = (const float*)d_in[1];
  const float* CK = (const float*)d_in[2];
  const float* QL = (const float*)d_in[3];
  const float* RL = (const float*)d_in[4];
  const float* initm = (const float*)d_in[5];
  const float* initc = (const float*)d_in[6];
  const float* Wih0 = (const float*)d_in[7];
  const float* Whh0 = (const float*)d_in[8];
  const float* bih0 = (const float*)d_in[9];
  const float* bhh0 = (const float*)d_in[10];
  const float* Wih1 = (const float*)d_in[11];
  const float* Whh1 = (const float*)d_in[12];
  const float* bih1 = (const float*)d_in[13];
  const float* bhh1 = (const float*)d_in[14];
  const float* Wout = (const float*)d_in[15];
  const float* bout = (const float*)d_in[16];
  float* ws = (float*)d_ws;
  float* out = (float*)d_out;

  ssm_prep_kernel<<<256, 256, 0, stream>>>(Wih0, Whh0, Wih1, Whh1, bih0, bhh0, bih1, bhh1,
                                           QL, RL, ws);
  ssm_main_kernel<<<B_SZ, NTHR, 0, stream>>>(as_, AK, CK, initm, initc, Wout, bout, ws, out);
}